// Round 13
// baseline (398.624 us; speedup 1.0000x reference)
//
#include <hip/hip_runtime.h>
#include <math.h>

typedef unsigned short u16;
typedef unsigned int u32;
typedef __attribute__((ext_vector_type(8))) short short8;   // 8 bf16 (4 VGPRs)
typedef __attribute__((ext_vector_type(4))) float f32x4;

#define DIM 384
#define HID 1536

static __device__ __forceinline__ float bf2f(u32 b){ return __uint_as_float(b << 16); }
static __device__ __forceinline__ u16 f2bf(float f){
  u32 u = __float_as_uint(f);
  u32 r = (u + 0x7fffu + ((u >> 16) & 1u)) >> 16;
  return (u16)r;
}
// tanh-form GELU via sigmoid; |err| ~1e-4 in our operating range
static __device__ __forceinline__ float gelu_fast(float v){
  float u = v * fmaf(0.0713548162726f, v * v, 1.59576912161f);
  float e = __builtin_amdgcn_exp2f(-1.44269504089f * u);
  return v * __builtin_amdgcn_rcpf(1.0f + e);
}
// async global->LDS, 16B/lane; LDS dest = wave-uniform base + lane*16
static __device__ __forceinline__ void gload_lds16(const u16* g, u16* l){
  __builtin_amdgcn_global_load_lds(
      (__attribute__((address_space(1))) void*)(void*)const_cast<u16*>(g),
      (__attribute__((address_space(3))) void*)(void*)l, 16, 0, 0);
}

// ---------------- LayerNorm: f32 in, bf16 out ------------------------------
__global__ __launch_bounds__(256) void ln_kernel(const float* __restrict__ x,
    const float* __restrict__ sc, const float* __restrict__ bi, u16* __restrict__ y){
  int lane = threadIdx.x & 63;
  int row = blockIdx.x * 4 + (threadIdx.x >> 6);
  const float* xr = x + (size_t)row * DIM;
  float v[6];
  float s = 0.f, sq = 0.f;
#pragma unroll
  for (int i = 0; i < 6; ++i){
    float f = xr[lane + 64*i];
    v[i] = f; s += f; sq += f*f;
  }
#pragma unroll
  for (int o = 1; o < 64; o <<= 1){ s += __shfl_xor(s, o); sq += __shfl_xor(sq, o); }
  float mean = s * (1.0f/DIM);
  float var = sq * (1.0f/DIM) - mean*mean;
  float inv = rsqrtf(var + 1e-5f);
  u16* yr = y + (size_t)row * DIM;
#pragma unroll
  for (int i = 0; i < 6; ++i){
    int c = lane + 64*i;
    yr[c] = f2bf((v[i] - mean) * inv * sc[c] + bi[c]);
  }
}

// ---------------- 3D RoPE, in-place on q (bf16) ----------------------------
__global__ __launch_bounds__(256) void rope_kernel(u16* __restrict__ q,
    const int* __restrict__ Tp, const int* __restrict__ Hp, const int* __restrict__ Wp,
    int Mtok){
  int idx = blockIdx.x * 256 + threadIdx.x;   // one thread per rotated pair
  int tok = idx / 192;                         // 192 pairs per token
  if (tok >= Mtok) return;
  int p = idx - tok * 192;
  int H = *Hp, W = *Wp, T = *Tp;
  int HW = H * W;
  int Ns = T * HW;
  int n = tok % Ns;
  int head = p / 12;
  int pp = p - head * 12;
  int s = pp >> 2, f = pp & 3;
  float pos;
  if (s == 0)      pos = (float)(n / HW);
  else if (s == 1) pos = (float)((n / W) % H);
  else             pos = (float)(n % W);
  const float LOG2_10000 = 13.28771237954945f;
  float inv = __builtin_amdgcn_exp2f(-0.25f * (float)f * LOG2_10000);
  float ang = pos * inv;
  float sn = __sinf(ang), cs = __cosf(ang);
  size_t base = (size_t)tok * DIM + head * 24 + s * 8 + 2 * f;
  u32 u = *(u32*)(q + base);
  float x1 = bf2f(u & 0xffffu), x2 = bf2f(u >> 16);
  float y1 = x1 * cs - x2 * sn;
  float y2 = x1 * sn + x2 * cs;
  *(u32*)(q + base) = (u32)f2bf(y1) | ((u32)f2bf(y2) << 16);
}

// ---------------- merged weight prep: all transposes + bias3, ONE launch ---
// Slice table (z): 0 qw->qwT, 1 ow->owT, 2 tw1->w1T, 3-5 cw1[i]->cw1T+i*W11
// (all 384x1536, ds=384), 6 tw2->w2T (1536x384, ds=1536), 7-9 cw2[i]->
// cw2T+i*1536 (1536x384, ds=4608). Transpose math byte-identical to the
// proven per-slice template; grid (48,48,10) with block-uniform guards.
// Block (0,0,0) additionally computes cb2s = sum of 3 cb2 vectors.
__global__ __launch_bounds__(256) void prep_kernel(
    const float* __restrict__ qw,  const float* __restrict__ ow,
    const float* __restrict__ tw1, const float* __restrict__ cw1,
    const float* __restrict__ tw2, const float* __restrict__ cw2,
    const float* __restrict__ cb2,
    u16* __restrict__ qwT, u16* __restrict__ owT, u16* __restrict__ w1T,
    u16* __restrict__ cw1T, u16* __restrict__ w2T, u16* __restrict__ cw2T,
    float* __restrict__ cb2s){
  const int W11 = DIM * HID;
  if (blockIdx.z == 0 && blockIdx.x == 0 && blockIdx.y == 0){
    for (int n = threadIdx.x; n < 384; n += 256)
      cb2s[n] = cb2[n] + cb2[384 + n] + cb2[768 + n];
  }
  const float* src; u16* dst; int R, C, ds;
  switch (blockIdx.z){
    case 0: src = qw;           dst = qwT;          R = 384;  C = 384;  ds = 384;  break;
    case 1: src = ow;           dst = owT;          R = 384;  C = 384;  ds = 384;  break;
    case 2: src = tw1;          dst = w1T;          R = 384;  C = 1536; ds = 384;  break;
    case 3: src = cw1;          dst = cw1T;         R = 384;  C = 1536; ds = 384;  break;
    case 4: src = cw1 + W11;    dst = cw1T + W11;   R = 384;  C = 1536; ds = 384;  break;
    case 5: src = cw1 + 2*W11;  dst = cw1T + 2*W11; R = 384;  C = 1536; ds = 384;  break;
    case 6: src = tw2;          dst = w2T;          R = 1536; C = 384;  ds = 1536; break;
    case 7: src = cw2;          dst = cw2T;         R = 1536; C = 384;  ds = 4608; break;
    case 8: src = cw2 + W11;    dst = cw2T + 1536;  R = 1536; C = 384;  ds = 4608; break;
    default: src = cw2 + 2*W11; dst = cw2T + 3072;  R = 1536; C = 384;  ds = 4608; break;
  }
  int c0 = blockIdx.x * 32, r0 = blockIdx.y * 32;
  if (c0 >= C || r0 >= R) return;          // block-uniform -> safe w/ barrier
  __shared__ u16 t[32][33];
  int tx = threadIdx.x & 31, ty = threadIdx.x >> 5;  // 32 x 8
#pragma unroll
  for (int i = 0; i < 4; ++i)
    t[ty + 8*i][tx] = f2bf(src[(size_t)(r0 + ty + 8*i) * C + c0 + tx]);
  __syncthreads();
#pragma unroll
  for (int i = 0; i < 4; ++i)
    dst[(size_t)(c0 + ty + 8*i) * ds + r0 + tx] = t[tx][ty + 8*i];
}

// ---------------- MFMA GEMM (R0-verified): C = A[M,K] @ Bt[N,K]^T ----------
enum { E_NONE = 0, E_BIAS = 1, E_RES_F32 = 3, E_FINAL = 5 };

template<int BM, int N, int K, int EPI>
__global__ __launch_bounds__(256) void gemm_kernel(
    const u16* __restrict__ A, const u16* __restrict__ Bt,
    void* __restrict__ Cv, const float* __restrict__ bias,
    const float* __restrict__ res, float* __restrict__ accbuf){
  constexpr int BN = 128, BK = 64;
  constexpr int MT = BM / 32, NT = 4;
  constexpr int AIT = BM / 32, BIT = 4;
  __shared__ __align__(16) u16 As[BM * BK];
  __shared__ __align__(16) u16 Bs[BN * BK];
  const int tid = threadIdx.x;
  const int lane = tid & 63;
  const int wv = tid >> 6;
  const int wm = (wv >> 1) * (BM / 2);
  const int wn = (wv & 1) * 64;
  const int quad = lane >> 4;
  const int l16 = lane & 15;
  const int rsw = l16 & 7;
  const size_t m0 = (size_t)blockIdx.x * BM;
  const int n0 = blockIdx.y * BN;
  const int srow = lane >> 3;
  const int scol = ((lane & 7) ^ srow) * 8;

  f32x4 acc[MT][NT];
  const f32x4 zero = {0.f, 0.f, 0.f, 0.f};
#pragma unroll
  for (int mt = 0; mt < MT; ++mt)
#pragma unroll
    for (int nt = 0; nt < NT; ++nt) acc[mt][nt] = zero;

  for (int kt = 0; kt < K; kt += BK){
#pragma unroll
    for (int i = 0; i < AIT; ++i){
      int seg = i * 4 + wv;
      gload_lds16(A + (m0 + (size_t)(seg * 8 + srow)) * K + kt + scol, As + seg * 512);
    }
#pragma unroll
    for (int i = 0; i < BIT; ++i){
      int seg = i * 4 + wv;
      gload_lds16(Bt + (size_t)(n0 + seg * 8 + srow) * K + kt + scol, Bs + seg * 512);
    }
    __syncthreads();
#pragma unroll
    for (int kk = 0; kk < 2; ++kk){
      short8 af[MT], bfr[NT];
#pragma unroll
      for (int mt = 0; mt < MT; ++mt)
        af[mt] = *(const short8*)(As + (wm + mt*16 + l16) * BK + (((kk*4 + quad) ^ rsw) << 3));
#pragma unroll
      for (int nt = 0; nt < NT; ++nt)
        bfr[nt] = *(const short8*)(Bs + (wn + nt*16 + l16) * BK + (((kk*4 + quad) ^ rsw) << 3));
#pragma unroll
      for (int mt = 0; mt < MT; ++mt)
#pragma unroll
        for (int nt = 0; nt < NT; ++nt)
          acc[mt][nt] = __builtin_amdgcn_mfma_f32_16x16x32_bf16(af[mt], bfr[nt], acc[mt][nt], 0, 0, 0);
    }
    __syncthreads();
  }

  // epilogue: C/D mapping col = lane&15, row = quad*4 + reg  [m89-verified]
#pragma unroll
  for (int mt = 0; mt < MT; ++mt){
#pragma unroll
    for (int nt = 0; nt < NT; ++nt){
      int ncol = n0 + wn + nt*16 + l16;
      float bv = (EPI != E_NONE) ? bias[ncol] : 0.f;
      size_t mbase = m0 + wm + mt*16 + quad*4;
#pragma unroll
      for (int r = 0; r < 4; ++r){
        size_t off = (mbase + r) * N + ncol;
        float vv = acc[mt][nt][r];
        if      (EPI == E_NONE)      ((u16*)Cv)[off] = f2bf(vv);
        else if (EPI == E_BIAS)      ((u16*)Cv)[off] = f2bf(vv + bv);
        else /* E_RES_F32 */         accbuf[off] = vv + bv + res[off];
      }
    }
  }
}

// ---------------- Up-GEMM v2: C = gelu(A @ Bt^T + bias) --------------------
// 512 threads (8 waves, 4m x 2n), BM=128 x BN=256, BK=64. Per wave per
// K-step: 32 MFMA vs 6 staging loads. LDS 48 KB; plain syncthreads schedule.
// Epilogue: pairwise v_cvt_pk_bf16_f32 on cols (c, c+16), stored at their
// NATURAL positions (identical addresses to the scalar-f2bf version -- no
// layout change, unlike the falsified pi-packing) -- saves ~6 VALU ops/pair.
template<int N, int K>
__global__ __launch_bounds__(512, 4) void gemm_up2_kernel(
    const u16* __restrict__ A, const u16* __restrict__ Bt,
    u16* __restrict__ C, const float* __restrict__ bias){
  constexpr int BK = 64;
  __shared__ __align__(16) u16 As[128 * BK];   // 16 KB
  __shared__ __align__(16) u16 Bs[256 * BK];   // 32 KB
  const int tid = threadIdx.x;
  const int lane = tid & 63;
  const int wv = tid >> 6;              // 0..7
  const int wm = (wv >> 1) * 32;        // 0,32,64,96
  const int wn = (wv & 1) * 128;        // 0,128
  const int quad = lane >> 4;
  const int l16 = lane & 15;
  const int rsw = l16 & 7;
  const size_t m0 = (size_t)blockIdx.x * 128;
  const int n0 = blockIdx.y * 256;
  const int srow = lane >> 3;
  const int scol = ((lane & 7) ^ srow) * 8;

  f32x4 acc[2][8];
  const f32x4 zero = {0.f, 0.f, 0.f, 0.f};
#pragma unroll
  for (int mt = 0; mt < 2; ++mt)
#pragma unroll
    for (int nt = 0; nt < 8; ++nt) acc[mt][nt] = zero;

  for (int kt = 0; kt < K; kt += BK){
    // A: 16 segs (2/wave); B: 32 segs (4/wave)
#pragma unroll
    for (int i = 0; i < 2; ++i){
      int seg = i * 8 + wv;
      gload_lds16(A + (m0 + (size_t)(seg * 8 + srow)) * K + kt + scol, As + seg * 512);
    }
#pragma unroll
    for (int i = 0; i < 4; ++i){
      int seg = i * 8 + wv;
      gload_lds16(Bt + (size_t)(n0 + seg * 8 + srow) * K + kt + scol, Bs + seg * 512);
    }
    __syncthreads();
#pragma unroll
    for (int kk = 0; kk < 2; ++kk){
      short8 af[2], bfr[8];
#pragma unroll
      for (int mt = 0; mt < 2; ++mt)
        af[mt] = *(const short8*)(As + (wm + mt*16 + l16) * BK + (((kk*4 + quad) ^ rsw) << 3));
#pragma unroll
      for (int nt = 0; nt < 8; ++nt)
        bfr[nt] = *(const short8*)(Bs + (wn + nt*16 + l16) * BK + (((kk*4 + quad) ^ rsw) << 3));
#pragma unroll
      for (int mt = 0; mt < 2; ++mt)
#pragma unroll
        for (int nt = 0; nt < 8; ++nt)
          acc[mt][nt] = __builtin_amdgcn_mfma_f32_16x16x32_bf16(af[mt], bfr[nt], acc[mt][nt], 0, 0, 0);
    }
    __syncthreads();
  }

  // epilogue: pairwise cvt_pk, natural-order stores (same addresses as R12)
#pragma unroll
  for (int mt = 0; mt < 2; ++mt){
#pragma unroll
    for (int j = 0; j < 4; ++j){
      int c0 = n0 + wn + j*32 + l16;       // col of acc[mt][2j]; pair at +16
      float bv0 = bias[c0];
      float bv1 = bias[c0 + 16];
      size_t mbase = m0 + wm + mt*16 + quad*4;
#pragma unroll
      for (int r = 0; r < 4; ++r){
        float g0 = gelu_fast(acc[mt][2*j][r] + bv0);
        float g1 = gelu_fast(acc[mt][2*j+1][r] + bv1);
        u32 pk;
        asm("v_cvt_pk_bf16_f32 %0, %1, %2" : "=v"(pk) : "v"(g0), "v"(g1));
        u16* row = C + (mbase + r) * N;
        row[c0]      = (u16)pk;
        row[c0 + 16] = (u16)(pk >> 16);
      }
    }
  }
}

// ---------------- Down-GEMM v2: C = A @ Bt^T (+bias / +res) ----------------
// 512 threads (8 waves, 4m x 2n), BM=128 x BN=128, BK=64. Per wave per
// K-step: 16 MFMA vs 4 staging loads. LDS 32 KB.
template<int N, int K, int EPI>
__global__ __launch_bounds__(512, 4) void gemm2_kernel(
    const u16* __restrict__ A, const u16* __restrict__ Bt,
    void* __restrict__ Cv, const float* __restrict__ bias,
    const float* __restrict__ accbuf){
  constexpr int BK = 64;
  __shared__ __align__(16) u16 As[128 * BK];   // 16 KB
  __shared__ __align__(16) u16 Bs[128 * BK];   // 16 KB
  const int tid = threadIdx.x;
  const int lane = tid & 63;
  const int wv = tid >> 6;              // 0..7
  const int wm = (wv >> 1) * 32;        // 0,32,64,96
  const int wn = (wv & 1) * 64;         // 0,64
  const int quad = lane >> 4;
  const int l16 = lane & 15;
  const int rsw = l16 & 7;
  const size_t m0 = (size_t)blockIdx.x * 128;
  const int n0 = blockIdx.y * 128;
  const int srow = lane >> 3;
  const int scol = ((lane & 7) ^ srow) * 8;

  f32x4 acc[2][4];
  const f32x4 zero = {0.f, 0.f, 0.f, 0.f};
#pragma unroll
  for (int mt = 0; mt < 2; ++mt)
#pragma unroll
    for (int nt = 0; nt < 4; ++nt) acc[mt][nt] = zero;

  for (int kt = 0; kt < K; kt += BK){
    // A: 16 segs (2/wave); B: 16 segs (2/wave)
#pragma unroll
    for (int i = 0; i < 2; ++i){
      int seg = i * 8 + wv;
      gload_lds16(A + (m0 + (size_t)(seg * 8 + srow)) * K + kt + scol, As + seg * 512);
      gload_lds16(Bt + (size_t)(n0 + seg * 8 + srow) * K + kt + scol, Bs + seg * 512);
    }
    __syncthreads();
#pragma unroll
    for (int kk = 0; kk < 2; ++kk){
      short8 af[2], bfr[4];
#pragma unroll
      for (int mt = 0; mt < 2; ++mt)
        af[mt] = *(const short8*)(As + (wm + mt*16 + l16) * BK + (((kk*4 + quad) ^ rsw) << 3));
#pragma unroll
      for (int nt = 0; nt < 4; ++nt)
        bfr[nt] = *(const short8*)(Bs + (wn + nt*16 + l16) * BK + (((kk*4 + quad) ^ rsw) << 3));
#pragma unroll
      for (int mt = 0; mt < 2; ++mt)
#pragma unroll
        for (int nt = 0; nt < 4; ++nt)
          acc[mt][nt] = __builtin_amdgcn_mfma_f32_16x16x32_bf16(af[mt], bfr[nt], acc[mt][nt], 0, 0, 0);
    }
    __syncthreads();
  }

  // epilogue: C/D mapping col = lane&15, row = quad*4 + reg
#pragma unroll
  for (int mt = 0; mt < 2; ++mt){
#pragma unroll
    for (int nt = 0; nt < 4; ++nt){
      int ncol = n0 + wn + nt*16 + l16;
      float bv = bias[ncol];
      size_t mbase = m0 + wm + mt*16 + quad*4;
#pragma unroll
      for (int r = 0; r < 4; ++r){
        size_t off = (mbase + r) * N + ncol;
        float vv = acc[mt][nt][r] + bv;
        if (EPI == E_BIAS) ((u16*)Cv)[off] = f2bf(vv);
        else /* E_FINAL */ ((float*)Cv)[off] = accbuf[off] + vv;
      }
    }
  }
}

extern "C" void kernel_launch(void* const* d_in, const int* in_sizes, int n_in,
                              void* d_out, int out_size, void* d_ws, size_t ws_size,
                              hipStream_t stream) {
  const int W11 = DIM * HID;   // 589824
  const float* x   = (const float*)d_in[0];
  const float* n1s = (const float*)d_in[1];
  const float* n1b = (const float*)d_in[2];
  const float* n2s = (const float*)d_in[3];
  const float* n2b = (const float*)d_in[4];
  const float* qw  = (const float*)d_in[5];
  const float* tw1 = (const float*)d_in[6] + 4 * W11;  // titan_w1[4]
  const float* tb1 = (const float*)d_in[7] + 4 * HID;  // titan_b1[4]
  const float* tw2 = (const float*)d_in[8] + 4 * W11;  // titan_w2[4]
  const float* tb2 = (const float*)d_in[9] + 4 * DIM;  // titan_b2[4]
  const float* ow  = (const float*)d_in[10];
  const float* ob  = (const float*)d_in[11];
  const float* cw1 = (const float*)d_in[12];
  const float* cb1 = (const float*)d_in[13];
  const float* cw2 = (const float*)d_in[14];
  const float* cb2 = (const float*)d_in[15];
  const int* Tp = (const int*)d_in[16];
  const int* Hp = (const int*)d_in[17];
  const int* Wp = (const int*)d_in[18];
  const int M = in_sizes[0] / DIM;   // 16384 tokens

  char* ws = (char*)d_ws;
  if (ws_size < 198772224u) return;
  u16*  y    = (u16*) (ws + 0);            // M x 384 bf16
  u16*  h    = (u16*) (ws + 12582912);     // M x 4608 bf16 (h / h_cat)
  float* x2  = (float*)(ws + 163577856);   // M x 384 f32
  u16*  qwT  = (u16*) (ws + 188743680);    // 384 x 384
  u16*  owT  = (u16*) (ws + 189038592);    // 384 x 384
  u16*  w1T  = (u16*) (ws + 189333504);    // 1536 x 384
  u16*  w2T  = (u16*) (ws + 190513152);    // 384 x 1536
  u16*  cw1T = (u16*) (ws + 191692800);    // 4608 x 384 (3 stacked)
  u16*  cw2T = (u16*) (ws + 195231744);    // 384 x 4608 (K-stacked)
  float* cb2s = (float*)(ws + 198770688);  // 384 f32
  u16*  qb   = (u16*)d_out;                // bf16 scratch: q, then t1

  // 1. ALL weight prep (4 transposes + bias3) in ONE launch
  prep_kernel<<<dim3(48,48,10),256,0,stream>>>(
      qw, ow, tw1, cw1, tw2, cw2, cb2,
      qwT, owT, w1T, cw1T, w2T, cw2T, cb2s);

  // 2. y = LN1(x)
  ln_kernel<<<M/4,256,0,stream>>>(x, n1s, n1b, y);
  // 3. q = y @ q_w   (bf16, into d_out)
  gemm_kernel<64,384,384,E_NONE><<<dim3(M/64,3),256,0,stream>>>(y, qwT, qb, nullptr, nullptr, nullptr);
  // 4. RoPE(q) in-place
  rope_kernel<<<(M*192)/256,256,0,stream>>>(qb, Tp, Hp, Wp, M);
  // 5. h = gelu(q @ w1 + b1)
  gemm_up2_kernel<1536,384><<<dim3(M/128,6),512,0,stream>>>(qb, w1T, h, tb1);
  // 6. t1 = h @ w2 + b2   (bf16, into d_out)
  gemm2_kernel<384,1536,E_BIAS><<<dim3(M/128,3),512,0,stream>>>(h, w2T, qb, tb2, nullptr);
  // 7. x2 = x + t1 @ out_w + out_b   (f32, into ws)
  gemm_kernel<64,384,384,E_RES_F32><<<dim3(M/64,3),256,0,stream>>>(qb, owT, nullptr, ob, x, x2);
  // 8. y2 = LN2(x2)
  ln_kernel<<<M/4,256,0,stream>>>(x2, n2s, n2b, y);
  // 9. h_cat = gelu(y @ cw1cat + cb1)
  gemm_up2_kernel<4608,384><<<dim3(M/128,18),512,0,stream>>>(y, cw1T, h, cb1);
  // 10. d_out = x2 + h_cat @ cw2cat + cb2s   (f32)
  gemm2_kernel<384,4608,E_FINAL><<<dim3(M/128,3),512,0,stream>>>(h, cw2T, d_out, cb2s, x2);
}

// Round 14
// 368.871 us; speedup vs baseline: 1.0807x; 1.0807x over previous
//
#include <hip/hip_runtime.h>
#include <math.h>

typedef unsigned short u16;
typedef unsigned int u32;
typedef __attribute__((ext_vector_type(8))) short short8;   // 8 bf16 (4 VGPRs)
typedef __attribute__((ext_vector_type(4))) float f32x4;

#define DIM 384
#define HID 1536

static __device__ __forceinline__ u16 f2bf(float f){
  u32 u = __float_as_uint(f);
  u32 r = (u + 0x7fffu + ((u >> 16) & 1u)) >> 16;
  return (u16)r;
}
// tanh-form GELU via sigmoid; |err| ~1e-4 in our operating range
static __device__ __forceinline__ float gelu_fast(float v){
  float u = v * fmaf(0.0713548162726f, v * v, 1.59576912161f);
  float e = __builtin_amdgcn_exp2f(-1.44269504089f * u);
  return v * __builtin_amdgcn_rcpf(1.0f + e);
}
// async global->LDS, 16B/lane; LDS dest = wave-uniform base + lane*16
static __device__ __forceinline__ void gload_lds16(const u16* g, u16* l){
  __builtin_amdgcn_global_load_lds(
      (__attribute__((address_space(1))) void*)(void*)const_cast<u16*>(g),
      (__attribute__((address_space(3))) void*)(void*)l, 16, 0, 0);
}

// ---------------- LayerNorm: f32 in, bf16 out ------------------------------
__global__ __launch_bounds__(256) void ln_kernel(const float* __restrict__ x,
    const float* __restrict__ sc, const float* __restrict__ bi, u16* __restrict__ y){
  int lane = threadIdx.x & 63;
  int row = blockIdx.x * 4 + (threadIdx.x >> 6);
  const float* xr = x + (size_t)row * DIM;
  float v[6];
  float s = 0.f, sq = 0.f;
#pragma unroll
  for (int i = 0; i < 6; ++i){
    float f = xr[lane + 64*i];
    v[i] = f; s += f; sq += f*f;
  }
#pragma unroll
  for (int o = 1; o < 64; o <<= 1){ s += __shfl_xor(s, o); sq += __shfl_xor(sq, o); }
  float mean = s * (1.0f/DIM);
  float var = sq * (1.0f/DIM) - mean*mean;
  float inv = rsqrtf(var + 1e-5f);
  u16* yr = y + (size_t)row * DIM;
#pragma unroll
  for (int i = 0; i < 6; ++i){
    int c = lane + 64*i;
    yr[c] = f2bf((v[i] - mean) * inv * sc[c] + bi[c]);
  }
}

// ---------------- merged weight prep: transposes + bias3 + rope table ------
// Slices (z): 0 qw->qwT, 1 ow->owT, 2 tw1->w1T, 3-5 cw1[i]->cw1T+i*W11
// (384x1536, ds=384), 6 tw2->w2T (1536x384, ds=1536), 7-9 cw2[i] (ds=4608),
// 10: rope sincos table rtab[c*M + row], c = s*4+f (12 classes), float2
// {sin,cos} of pos(s,row)*10000^(-f/4). Block (0,0,0) also computes cb2s.
__global__ __launch_bounds__(256) void prep_kernel(
    const float* __restrict__ qw,  const float* __restrict__ ow,
    const float* __restrict__ tw1, const float* __restrict__ cw1,
    const float* __restrict__ tw2, const float* __restrict__ cw2,
    const float* __restrict__ cb2,
    u16* __restrict__ qwT, u16* __restrict__ owT, u16* __restrict__ w1T,
    u16* __restrict__ cw1T, u16* __restrict__ w2T, u16* __restrict__ cw2T,
    float* __restrict__ cb2s,
    const int* __restrict__ Tp, const int* __restrict__ Hp,
    const int* __restrict__ Wp, float2* __restrict__ rtab, int Mtot){
  const int W11 = DIM * HID;
  if (blockIdx.z == 10){
    int lin = ((int)blockIdx.y * 48 + (int)blockIdx.x) * 256 + (int)threadIdx.x;
    int tot = 12 * Mtot;
    if (lin < tot){
      int c = lin / Mtot, row = lin - c * Mtot;
      int T = *Tp, Hh = *Hp, Ww = *Wp;
      int HW = Hh * Ww, Ns = T * HW;
      int n = row % Ns;
      int s = c >> 2, f = c & 3;
      float pos = (s == 0) ? (float)(n / HW)
                : (s == 1) ? (float)((n / Ww) % Hh)
                           : (float)(n % Ww);
      const float LOG2_10000 = 13.28771237954945f;
      float inv = __builtin_amdgcn_exp2f(-0.25f * (float)f * LOG2_10000);
      float ang = pos * inv;
      rtab[lin] = make_float2(__sinf(ang), __cosf(ang));
    }
    return;
  }
  if (blockIdx.z == 0 && blockIdx.x == 0 && blockIdx.y == 0){
    for (int n = threadIdx.x; n < 384; n += 256)
      cb2s[n] = cb2[n] + cb2[384 + n] + cb2[768 + n];
  }
  const float* src; u16* dst; int R, C, ds;
  switch (blockIdx.z){
    case 0: src = qw;           dst = qwT;          R = 384;  C = 384;  ds = 384;  break;
    case 1: src = ow;           dst = owT;          R = 384;  C = 384;  ds = 384;  break;
    case 2: src = tw1;          dst = w1T;          R = 384;  C = 1536; ds = 384;  break;
    case 3: src = cw1;          dst = cw1T;         R = 384;  C = 1536; ds = 384;  break;
    case 4: src = cw1 + W11;    dst = cw1T + W11;   R = 384;  C = 1536; ds = 384;  break;
    case 5: src = cw1 + 2*W11;  dst = cw1T + 2*W11; R = 384;  C = 1536; ds = 384;  break;
    case 6: src = tw2;          dst = w2T;          R = 1536; C = 384;  ds = 1536; break;
    case 7: src = cw2;          dst = cw2T;         R = 1536; C = 384;  ds = 4608; break;
    case 8: src = cw2 + W11;    dst = cw2T + 1536;  R = 1536; C = 384;  ds = 4608; break;
    default: src = cw2 + 2*W11; dst = cw2T + 3072;  R = 1536; C = 384;  ds = 4608; break;
  }
  int c0 = blockIdx.x * 32, r0 = blockIdx.y * 32;
  if (c0 >= C || r0 >= R) return;          // block-uniform -> safe w/ barrier
  __shared__ u16 t[32][33];
  int tx = threadIdx.x & 31, ty = threadIdx.x >> 5;  // 32 x 8
#pragma unroll
  for (int i = 0; i < 4; ++i)
    t[ty + 8*i][tx] = f2bf(src[(size_t)(r0 + ty + 8*i) * C + c0 + tx]);
  __syncthreads();
#pragma unroll
  for (int i = 0; i < 4; ++i)
    dst[(size_t)(c0 + ty + 8*i) * ds + r0 + tx] = t[tx][ty + 8*i];
}

// ---------------- MFMA GEMM (R0-verified): C = A[M,K] @ Bt[N,K]^T ----------
enum { E_NONE = 0, E_BIAS = 1, E_RES_F32 = 3, E_FINAL = 5, E_ROPE = 6 };

// E_ROPE: apply 3D RoPE in the epilogue. Pairs are adjacent columns (2f,
// 2f+1) held by adjacent lanes (l16, l16^1) of the same quad/row, so the
// rotation is one __shfl_xor + fma using the prep-computed sincos table
// rtab[c*Mtot + row], c = ((ncol%24)>>3)*4 + ((ncol>>1)&3). Applied to f32
// accumulators BEFORE the single bf16 rounding (reference-closer numerics
// than the old bf16->rotate->bf16 path).
template<int BM, int N, int K, int EPI>
__global__ __launch_bounds__(256) void gemm_kernel(
    const u16* __restrict__ A, const u16* __restrict__ Bt,
    void* __restrict__ Cv, const float* __restrict__ bias,
    const float* __restrict__ res, float* __restrict__ accbuf,
    const float2* __restrict__ rtab, int Mtot){
  constexpr int BN = 128, BK = 64;
  constexpr int MT = BM / 32, NT = 4;
  constexpr int AIT = BM / 32, BIT = 4;
  __shared__ __align__(16) u16 As[BM * BK];
  __shared__ __align__(16) u16 Bs[BN * BK];
  const int tid = threadIdx.x;
  const int lane = tid & 63;
  const int wv = tid >> 6;
  const int wm = (wv >> 1) * (BM / 2);
  const int wn = (wv & 1) * 64;
  const int quad = lane >> 4;
  const int l16 = lane & 15;
  const int rsw = l16 & 7;
  const size_t m0 = (size_t)blockIdx.x * BM;
  const int n0 = blockIdx.y * BN;
  const int srow = lane >> 3;
  const int scol = ((lane & 7) ^ srow) * 8;

  f32x4 acc[MT][NT];
  const f32x4 zero = {0.f, 0.f, 0.f, 0.f};
#pragma unroll
  for (int mt = 0; mt < MT; ++mt)
#pragma unroll
    for (int nt = 0; nt < NT; ++nt) acc[mt][nt] = zero;

  for (int kt = 0; kt < K; kt += BK){
#pragma unroll
    for (int i = 0; i < AIT; ++i){
      int seg = i * 4 + wv;
      gload_lds16(A + (m0 + (size_t)(seg * 8 + srow)) * K + kt + scol, As + seg * 512);
    }
#pragma unroll
    for (int i = 0; i < BIT; ++i){
      int seg = i * 4 + wv;
      gload_lds16(Bt + (size_t)(n0 + seg * 8 + srow) * K + kt + scol, Bs + seg * 512);
    }
    __syncthreads();
#pragma unroll
    for (int kk = 0; kk < 2; ++kk){
      short8 af[MT], bfr[NT];
#pragma unroll
      for (int mt = 0; mt < MT; ++mt)
        af[mt] = *(const short8*)(As + (wm + mt*16 + l16) * BK + (((kk*4 + quad) ^ rsw) << 3));
#pragma unroll
      for (int nt = 0; nt < NT; ++nt)
        bfr[nt] = *(const short8*)(Bs + (wn + nt*16 + l16) * BK + (((kk*4 + quad) ^ rsw) << 3));
#pragma unroll
      for (int mt = 0; mt < MT; ++mt)
#pragma unroll
        for (int nt = 0; nt < NT; ++nt)
          acc[mt][nt] = __builtin_amdgcn_mfma_f32_16x16x32_bf16(af[mt], bfr[nt], acc[mt][nt], 0, 0, 0);
    }
    __syncthreads();
  }

  // epilogue: C/D mapping col = lane&15, row = quad*4 + reg  [m89-verified]
#pragma unroll
  for (int mt = 0; mt < MT; ++mt){
#pragma unroll
    for (int nt = 0; nt < NT; ++nt){
      int ncol = n0 + wn + nt*16 + l16;
      float bv = (EPI == E_BIAS || EPI == E_RES_F32 || EPI == E_FINAL) ? bias[ncol] : 0.f;
      size_t mbase = m0 + wm + mt*16 + quad*4;
      int cls = ((ncol % 24) >> 3) * 4 + ((ncol >> 1) & 3);   // rope class (E_ROPE)
      float sgnbit = (ncol & 1) ? 1.f : -1.f;
#pragma unroll
      for (int r = 0; r < 4; ++r){
        size_t off = (mbase + r) * N + ncol;
        float vv = acc[mt][nt][r];
        if (EPI == E_NONE) ((u16*)Cv)[off] = f2bf(vv);
        else if (EPI == E_ROPE){
          float2 sc = rtab[(size_t)cls * Mtot + (mbase + r)];
          float part = __shfl_xor(vv, 1);
          ((u16*)Cv)[off] = f2bf(vv * sc.y + sgnbit * part * sc.x);
        }
        else if (EPI == E_BIAS)    ((u16*)Cv)[off] = f2bf(vv + bv);
        else if (EPI == E_RES_F32) accbuf[off] = vv + bv + res[off];
        else /* E_FINAL */         ((float*)Cv)[off] = accbuf[off] + vv + bv;
      }
    }
  }
}

// ---------------- Up-GEMM v2: C = gelu(A @ Bt^T + bias) --------------------
// 512 threads (8 waves, 4m x 2n), BM=128 x BN=256, BK=64. Per wave per
// K-step: 32 MFMA vs 6 staging loads. LDS 48 KB; plain syncthreads schedule.
// Epilogue: pairwise v_cvt_pk_bf16_f32 on cols (c, c+16), natural-position
// stores (identical addresses to scalar f2bf; no layout change).
template<int N, int K>
__global__ __launch_bounds__(512, 4) void gemm_up2_kernel(
    const u16* __restrict__ A, const u16* __restrict__ Bt,
    u16* __restrict__ C, const float* __restrict__ bias){
  constexpr int BK = 64;
  __shared__ __align__(16) u16 As[128 * BK];   // 16 KB
  __shared__ __align__(16) u16 Bs[256 * BK];   // 32 KB
  const int tid = threadIdx.x;
  const int lane = tid & 63;
  const int wv = tid >> 6;              // 0..7
  const int wm = (wv >> 1) * 32;        // 0,32,64,96
  const int wn = (wv & 1) * 128;        // 0,128
  const int quad = lane >> 4;
  const int l16 = lane & 15;
  const int rsw = l16 & 7;
  const size_t m0 = (size_t)blockIdx.x * 128;
  const int n0 = blockIdx.y * 256;
  const int srow = lane >> 3;
  const int scol = ((lane & 7) ^ srow) * 8;

  f32x4 acc[2][8];
  const f32x4 zero = {0.f, 0.f, 0.f, 0.f};
#pragma unroll
  for (int mt = 0; mt < 2; ++mt)
#pragma unroll
    for (int nt = 0; nt < 8; ++nt) acc[mt][nt] = zero;

  for (int kt = 0; kt < K; kt += BK){
    // A: 16 segs (2/wave); B: 32 segs (4/wave)
#pragma unroll
    for (int i = 0; i < 2; ++i){
      int seg = i * 8 + wv;
      gload_lds16(A + (m0 + (size_t)(seg * 8 + srow)) * K + kt + scol, As + seg * 512);
    }
#pragma unroll
    for (int i = 0; i < 4; ++i){
      int seg = i * 8 + wv;
      gload_lds16(Bt + (size_t)(n0 + seg * 8 + srow) * K + kt + scol, Bs + seg * 512);
    }
    __syncthreads();
#pragma unroll
    for (int kk = 0; kk < 2; ++kk){
      short8 af[2], bfr[8];
#pragma unroll
      for (int mt = 0; mt < 2; ++mt)
        af[mt] = *(const short8*)(As + (wm + mt*16 + l16) * BK + (((kk*4 + quad) ^ rsw) << 3));
#pragma unroll
      for (int nt = 0; nt < 8; ++nt)
        bfr[nt] = *(const short8*)(Bs + (wn + nt*16 + l16) * BK + (((kk*4 + quad) ^ rsw) << 3));
#pragma unroll
      for (int mt = 0; mt < 2; ++mt)
#pragma unroll
        for (int nt = 0; nt < 8; ++nt)
          acc[mt][nt] = __builtin_amdgcn_mfma_f32_16x16x32_bf16(af[mt], bfr[nt], acc[mt][nt], 0, 0, 0);
    }
    __syncthreads();
  }

  // epilogue: pairwise cvt_pk, natural-order stores
#pragma unroll
  for (int mt = 0; mt < 2; ++mt){
#pragma unroll
    for (int j = 0; j < 4; ++j){
      int c0 = n0 + wn + j*32 + l16;       // col of acc[mt][2j]; pair at +16
      float bv0 = bias[c0];
      float bv1 = bias[c0 + 16];
      size_t mbase = m0 + wm + mt*16 + quad*4;
#pragma unroll
      for (int r = 0; r < 4; ++r){
        float g0 = gelu_fast(acc[mt][2*j][r] + bv0);
        float g1 = gelu_fast(acc[mt][2*j+1][r] + bv1);
        u32 pk;
        asm("v_cvt_pk_bf16_f32 %0, %1, %2" : "=v"(pk) : "v"(g0), "v"(g1));
        u16* row = C + (mbase + r) * N;
        row[c0]      = (u16)pk;
        row[c0 + 16] = (u16)(pk >> 16);
      }
    }
  }
}

// ---------------- Down-GEMM v2: C = A @ Bt^T (+bias / +res) ----------------
// 512 threads (8 waves, 4m x 2n), BM=128 x BN=128, BK=64. Per wave per
// K-step: 16 MFMA vs 4 staging loads. LDS 32 KB.
template<int N, int K, int EPI>
__global__ __launch_bounds__(512, 4) void gemm2_kernel(
    const u16* __restrict__ A, const u16* __restrict__ Bt,
    void* __restrict__ Cv, const float* __restrict__ bias,
    const float* __restrict__ accbuf){
  constexpr int BK = 64;
  __shared__ __align__(16) u16 As[128 * BK];   // 16 KB
  __shared__ __align__(16) u16 Bs[128 * BK];   // 16 KB
  const int tid = threadIdx.x;
  const int lane = tid & 63;
  const int wv = tid >> 6;              // 0..7
  const int wm = (wv >> 1) * 32;        // 0,32,64,96
  const int wn = (wv & 1) * 64;         // 0,64
  const int quad = lane >> 4;
  const int l16 = lane & 15;
  const int rsw = l16 & 7;
  const size_t m0 = (size_t)blockIdx.x * 128;
  const int n0 = blockIdx.y * 128;
  const int srow = lane >> 3;
  const int scol = ((lane & 7) ^ srow) * 8;

  f32x4 acc[2][4];
  const f32x4 zero = {0.f, 0.f, 0.f, 0.f};
#pragma unroll
  for (int mt = 0; mt < 2; ++mt)
#pragma unroll
    for (int nt = 0; nt < 4; ++nt) acc[mt][nt] = zero;

  for (int kt = 0; kt < K; kt += BK){
    // A: 16 segs (2/wave); B: 16 segs (2/wave)
#pragma unroll
    for (int i = 0; i < 2; ++i){
      int seg = i * 8 + wv;
      gload_lds16(A + (m0 + (size_t)(seg * 8 + srow)) * K + kt + scol, As + seg * 512);
      gload_lds16(Bt + (size_t)(n0 + seg * 8 + srow) * K + kt + scol, Bs + seg * 512);
    }
    __syncthreads();
#pragma unroll
    for (int kk = 0; kk < 2; ++kk){
      short8 af[2], bfr[4];
#pragma unroll
      for (int mt = 0; mt < 2; ++mt)
        af[mt] = *(const short8*)(As + (wm + mt*16 + l16) * BK + (((kk*4 + quad) ^ rsw) << 3));
#pragma unroll
      for (int nt = 0; nt < 4; ++nt)
        bfr[nt] = *(const short8*)(Bs + (wn + nt*16 + l16) * BK + (((kk*4 + quad) ^ rsw) << 3));
#pragma unroll
      for (int mt = 0; mt < 2; ++mt)
#pragma unroll
        for (int nt = 0; nt < 4; ++nt)
          acc[mt][nt] = __builtin_amdgcn_mfma_f32_16x16x32_bf16(af[mt], bfr[nt], acc[mt][nt], 0, 0, 0);
    }
    __syncthreads();
  }

  // epilogue: C/D mapping col = lane&15, row = quad*4 + reg
#pragma unroll
  for (int mt = 0; mt < 2; ++mt){
#pragma unroll
    for (int nt = 0; nt < 4; ++nt){
      int ncol = n0 + wn + nt*16 + l16;
      float bv = bias[ncol];
      size_t mbase = m0 + wm + mt*16 + quad*4;
#pragma unroll
      for (int r = 0; r < 4; ++r){
        size_t off = (mbase + r) * N + ncol;
        float vv = acc[mt][nt][r] + bv;
        if (EPI == E_BIAS) ((u16*)Cv)[off] = f2bf(vv);
        else /* E_FINAL */ ((float*)Cv)[off] = accbuf[off] + vv;
      }
    }
  }
}

extern "C" void kernel_launch(void* const* d_in, const int* in_sizes, int n_in,
                              void* d_out, int out_size, void* d_ws, size_t ws_size,
                              hipStream_t stream) {
  const int W11 = DIM * HID;   // 589824
  const float* x   = (const float*)d_in[0];
  const float* n1s = (const float*)d_in[1];
  const float* n1b = (const float*)d_in[2];
  const float* n2s = (const float*)d_in[3];
  const float* n2b = (const float*)d_in[4];
  const float* qw  = (const float*)d_in[5];
  const float* tw1 = (const float*)d_in[6] + 4 * W11;  // titan_w1[4]
  const float* tb1 = (const float*)d_in[7] + 4 * HID;  // titan_b1[4]
  const float* tw2 = (const float*)d_in[8] + 4 * W11;  // titan_w2[4]
  const float* tb2 = (const float*)d_in[9] + 4 * DIM;  // titan_b2[4]
  const float* ow  = (const float*)d_in[10];
  const float* ob  = (const float*)d_in[11];
  const float* cw1 = (const float*)d_in[12];
  const float* cb1 = (const float*)d_in[13];
  const float* cw2 = (const float*)d_in[14];
  const float* cb2 = (const float*)d_in[15];
  const int* Tp = (const int*)d_in[16];
  const int* Hp = (const int*)d_in[17];
  const int* Wp = (const int*)d_in[18];
  const int M = in_sizes[0] / DIM;   // 16384 tokens

  char* ws = (char*)d_ws;
  if (ws_size < 198772224u) return;
  u16*  y    = (u16*) (ws + 0);            // M x 384 bf16
  u16*  h    = (u16*) (ws + 12582912);     // M x 4608 bf16 (h / h_cat)
  float2* rtab = (float2*)(ws + 12582912); // [12][M] sincos (h-region; dead until step 5)
  float* x2  = (float*)(ws + 163577856);   // M x 384 f32
  u16*  qwT  = (u16*) (ws + 188743680);    // 384 x 384
  u16*  owT  = (u16*) (ws + 189038592);    // 384 x 384
  u16*  w1T  = (u16*) (ws + 189333504);    // 1536 x 384
  u16*  w2T  = (u16*) (ws + 190513152);    // 384 x 1536
  u16*  cw1T = (u16*) (ws + 191692800);    // 4608 x 384 (3 stacked)
  u16*  cw2T = (u16*) (ws + 195231744);    // 384 x 4608 (K-stacked)
  float* cb2s = (float*)(ws + 198770688);  // 384 f32
  u16*  qb   = (u16*)d_out;                // bf16 scratch: q, then t1

  // 1. ALL weight prep (4 transposes + bias3 + rope sincos table), ONE launch
  prep_kernel<<<dim3(48,48,11),256,0,stream>>>(
      qw, ow, tw1, cw1, tw2, cw2, cb2,
      qwT, owT, w1T, cw1T, w2T, cw2T, cb2s,
      Tp, Hp, Wp, rtab, M);

  // 2. y = LN1(x)
  ln_kernel<<<M/4,256,0,stream>>>(x, n1s, n1b, y);
  // 3. q = rope(y @ q_w)   (bf16, into d_out; RoPE fused in epilogue)
  gemm_kernel<64,384,384,E_ROPE><<<dim3(M/64,3),256,0,stream>>>(
      y, qwT, qb, nullptr, nullptr, nullptr, rtab, M);
  // 4. h = gelu(q @ w1 + b1)
  gemm_up2_kernel<1536,384><<<dim3(M/128,6),512,0,stream>>>(qb, w1T, h, tb1);
  // 5. t1 = h @ w2 + b2   (bf16, into d_out)
  gemm2_kernel<384,1536,E_BIAS><<<dim3(M/128,3),512,0,stream>>>(h, w2T, qb, tb2, nullptr);
  // 6. x2 = x + t1 @ out_w + out_b   (f32, into ws)
  gemm_kernel<64,384,384,E_RES_F32><<<dim3(M/64,3),256,0,stream>>>(
      qb, owT, nullptr, ob, x, x2, nullptr, M);
  // 7. y2 = LN2(x2)
  ln_kernel<<<M/4,256,0,stream>>>(x2, n2s, n2b, y);
  // 8. h_cat = gelu(y @ cw1cat + cb1)
  gemm_up2_kernel<4608,384><<<dim3(M/128,18),512,0,stream>>>(y, cw1T, h, cb1);
  // 9. d_out = x2 + h_cat @ cw2cat + cb2s   (f32)
  gemm2_kernel<384,4608,E_FINAL><<<dim3(M/128,3),512,0,stream>>>(h, cw2T, d_out, cb2s, x2);
}